// Round 4
// baseline (1873.070 us; speedup 1.0000x reference)
//
#include <hip/hip_runtime.h>
#include <math.h>

#define D      1024
#define CD     16
#define CS     8192
#define ROWS   16384   // B*L
#define LN_EPS 1e-5f
#define KCHUNK 512            // codes per dist chunk
#define NCHUNK (CS / KCHUNK)  // 16

typedef __attribute__((ext_vector_type(8))) short short8;
typedef __attribute__((ext_vector_type(4))) float f32x4;
typedef __attribute__((ext_vector_type(16))) float f32x16;

__device__ inline unsigned short bf16_rne(float v) {
    unsigned u = __float_as_uint(v);
    unsigned r = u + 0x7FFFu + ((u >> 16) & 1u);
    return (unsigned short)(r >> 16);
}
__device__ inline short8 ld8(const unsigned short* p) { return *(const short8*)p; }

// exact 3-term bf16 split: v = a + b + c, dropped residual ~2^-27 rel
__device__ inline void split3(float v, unsigned short& a, unsigned short& b, unsigned short& c) {
    unsigned u = __float_as_uint(v);
    unsigned r = u + 0x7FFFu + ((u >> 16) & 1u);
    a = (unsigned short)(r >> 16);
    float r1 = v - __uint_as_float(r & 0xFFFF0000u);     // exact
    unsigned u1 = __float_as_uint(r1);
    unsigned r1b = u1 + 0x7FFFu + ((u1 >> 16) & 1u);
    b = (unsigned short)(r1b >> 16);
    float r2 = r1 - __uint_as_float(r1b & 0xFFFF0000u);  // exact
    c = bf16_rne(r2);
}

// -------------------------------------------------------------------------
// pack: blockIdx < 32 -> codebook 3-term split written in 32x32x16 MFMA
//       B-frag STREAM order:
//       code k: ci=k>>9, tt=(k>>5)&15, c31=k&31;
//       cbp[ci*24576 + tt*1536 + term*512 + (h*32+c31)*8 + j] = term(cd=h*8+j)
//       plus nhc[k] = -0.5||c||^2.  (verified exact in rounds 1-3)
//       blockIdx >= 32 -> W 3-term split in 16x16x32 MFMA-B-frag stream
//       order for proj_ln (unchanged).
// -------------------------------------------------------------------------
__global__ __launch_bounds__(256) void pack_all(const float* __restrict__ W,
                                                const float* __restrict__ cb,
                                                unsigned short* __restrict__ wb,
                                                unsigned short* __restrict__ cbp,
                                                float* __restrict__ nhc)
{
    const int t = threadIdx.x;
    if (blockIdx.x < 32) {
        int k = blockIdx.x * 256 + t;          // 0..8191
        const float* c = cb + (long)k * CD;
        int ci  = k >> 9;
        int tt  = (k >> 5) & 15;
        int c31 = k & 31;
        unsigned short* base = cbp + (size_t)ci * 24576 + tt * 1536;
        float csq = 0.f;
        unsigned short h0[16], h1[16], h2[16];
        #pragma unroll
        for (int d = 0; d < 16; ++d) {
            float v = c[d];
            csq = fmaf(v, v, csq);
            split3(v, h0[d], h1[d], h2[d]);
        }
        #pragma unroll
        for (int h = 0; h < 2; ++h) {
            short8 v0, v1, v2;
            #pragma unroll
            for (int j = 0; j < 8; ++j) {
                v0[j] = (short)h0[h * 8 + j];
                v1[j] = (short)h1[h * 8 + j];
                v2[j] = (short)h2[h * 8 + j];
            }
            int lofs = (h * 32 + c31) * 8;
            *(short8*)(base + lofs)        = v0;
            *(short8*)(base + 512 + lofs)  = v1;
            *(short8*)(base + 1024 + lofs) = v2;
        }
        nhc[k] = -0.5f * csq;
    } else {
        int tid = (blockIdx.x - 32) * 256 + t; // 0..6143
        int gk   = tid / 192;
        int rem  = tid % 192;
        int term = rem >> 6;
        int L    = rem & 63;
        int n = L & 15, q = L >> 4;
        const float* src = W + n * D + gk * 32 + q * 8;
        unsigned short* dst = wb + (size_t)tid * 8;
        #pragma unroll
        for (int j = 0; j < 8; ++j) {
            unsigned short h0, h1, h2;
            split3(src[j], h0, h1, h2);
            dst[j] = term == 0 ? h0 : (term == 1 ? h1 : h2);
        }
    }
}

// -------------------------------------------------------------------------
// proj_ln: z = LayerNorm(x @ W^T) fused, emitted as 3-term bf16 split.
// (unchanged from rounds 0-3; near the x-read memory floor)
// -------------------------------------------------------------------------
__global__ __launch_bounds__(256, 4) void proj_ln(const float* __restrict__ x,
                                                  const unsigned short* __restrict__ wb,
                                                  unsigned short* __restrict__ zp)
{
    __shared__ float part[3][64][4];   // waves 1..3 deposit here
    const int t = threadIdx.x;
    const int L = t & 63;
    const int kq = t >> 6;             // K-quarter
    const int rt = blockIdx.x;         // row-tile
    const int n = L & 15, q = L >> 4;

    const float* xrow = x + (size_t)(rt * 16 + n) * D + kq * 256 + q * 8;
    const unsigned short* wbase = wb + (size_t)(kq * 8) * 1536;

    f32x4 acc0 = {0.f, 0.f, 0.f, 0.f};
    f32x4 acc1 = {0.f, 0.f, 0.f, 0.f};
    #pragma unroll
    for (int kk = 0; kk < 8; ++kk) {
        float4 xa = *(const float4*)(xrow + kk * 32);
        float4 xb = *(const float4*)(xrow + kk * 32 + 4);
        const unsigned short* wp = wbase + (size_t)kk * 1536 + L * 8;
        short8 w0 = ld8(wp);
        short8 w1 = ld8(wp + 512);
        short8 w2 = ld8(wp + 1024);
        float vs[8] = {xa.x, xa.y, xa.z, xa.w, xb.x, xb.y, xb.z, xb.w};
        short8 x0, x1, x2;
        #pragma unroll
        for (int j = 0; j < 8; ++j) {
            unsigned short h0, h1, h2;
            split3(vs[j], h0, h1, h2);
            x0[j] = (short)h0; x1[j] = (short)h1; x2[j] = (short)h2;
        }
        // two independent chains (exact products >= 2^-24 kept on each)
        acc0 = __builtin_amdgcn_mfma_f32_16x16x32_bf16(x0, w0, acc0, 0, 0, 0);
        acc1 = __builtin_amdgcn_mfma_f32_16x16x32_bf16(x0, w1, acc1, 0, 0, 0);
        acc0 = __builtin_amdgcn_mfma_f32_16x16x32_bf16(x1, w0, acc0, 0, 0, 0);
        acc1 = __builtin_amdgcn_mfma_f32_16x16x32_bf16(x1, w1, acc1, 0, 0, 0);
        acc0 = __builtin_amdgcn_mfma_f32_16x16x32_bf16(x0, w2, acc0, 0, 0, 0);
        acc1 = __builtin_amdgcn_mfma_f32_16x16x32_bf16(x2, w0, acc1, 0, 0, 0);
    }

    if (kq != 0) {
        #pragma unroll
        for (int r = 0; r < 4; ++r) part[kq - 1][L][r] = acc0[r] + acc1[r];
    }
    __syncthreads();
    if (kq == 0) {
        // C/D layout: col n = channel (lane&15), row = q*4 + r
        #pragma unroll
        for (int r = 0; r < 4; ++r) {
            float zv = acc0[r] + acc1[r] + part[0][L][r] + part[1][L][r] + part[2][L][r];
            float s = zv;
            for (int m = 1; m < 16; m <<= 1) s += __shfl_xor(s, m, 64);
            float mu = s * (1.f / 16.f);
            float dd = zv - mu;
            float v2 = dd * dd;
            for (int m = 1; m < 16; m <<= 1) v2 += __shfl_xor(v2, m, 64);
            float var = v2 * (1.f / 16.f);
            float zn = dd / sqrtf(var + LN_EPS);
            unsigned short h0, h1, h2;
            split3(zn, h0, h1, h2);
            unsigned short* zr = zp + (size_t)(rt * 16 + q * 4 + r) * 48;
            zr[n] = h0; zr[16 + n] = h1; zr[32 + n] = h2;
        }
    }
}

// -------------------------------------------------------------------------
// dist_argmin: score = z.c - 0.5||c||^2 (argmin d2 == argmax score).
// 32x32x16 MFMA + linear LDS staging of the stream-order chunk (proven
// conflict-free in round 3). Round-4 change: RESIDENCY GEOMETRY ONLY.
// Block = 1024 threads = 16 waves, one 32-row tile each (512 rows/block);
// grid = 32x16 = 512 blocks = exactly 2 blocks/CU. LDS 50KB*2 = 100KB/CU
// fits; VGPR<=64 (measured 48) -> 8 waves/SIMD = 32 waves/CU = full
// occupancy, no tail generation (round 3: 34.6% occupancy, 3-of-4-resident
// tail). Inner loop byte-identical to round 3 (absmax 0.0).
// A: m=lane&31 (z row), k=(lane>>5)*8+j. B: n=lane&31 (code), same k.
// C/D: col=lane&31, row=(reg&3)+8*(reg>>2)+4*(lane>>5). Bias enters as the
// C operand of the 1st MFMA; winner tracked as 4-bit tt, full code
// reconstructed once before the cross-lane reduce.
// -------------------------------------------------------------------------
__global__ __launch_bounds__(1024, 8) void dist_argmin(const unsigned short* __restrict__ zp,
                                                       const unsigned short* __restrict__ cbp,
                                                       const float* __restrict__ nhc,
                                                       float* __restrict__ pbest,
                                                       int* __restrict__ pidx)
{
    __shared__ __align__(16) unsigned short cl[KCHUNK * 48];  // 48 KB, stream order
    __shared__ float ql[KCHUNK];                              // 2 KB
    const int t = threadIdx.x;
    const int kbase = blockIdx.y * KCHUNK;

    {   // linear stage preserves stream order: 48KB / (1024 thr * 16B) = 3 iters
        float4* dst = (float4*)cl;
        const float4* src = (const float4*)(cbp + (size_t)kbase * 48);
        #pragma unroll
        for (int i = 0; i < 3; ++i) dst[t + i * 1024] = src[t + i * 1024];
        if (t < KCHUNK / 4) ((float4*)ql)[t] = ((const float4*)(nhc + kbase))[t];
    }
    __syncthreads();

    const int L = t & 63;
    const int w = t >> 6;      // wave 0..15
    const int c31 = L & 31;    // code col (B n) / z row (A m)
    const int half = L >> 5;   // k-half selector

    const int rt = blockIdx.x * 16 + w;  // 32-row tile index (512 total)
    const unsigned short* zr = zp + (size_t)(rt * 32 + c31) * 48 + half * 8;
    short8 a0 = ld8(zr);        // z term-0 fragment
    short8 a1 = ld8(zr + 16);   // z term-1
    short8 a2 = ld8(zr + 32);   // z term-2

    const unsigned short* cstream = cl + L * 8;  // lane base; tt/term are imm offsets

    float best[16];
    int   bt[16];
    #pragma unroll
    for (int r = 0; r < 16; ++r) { best[r] = -INFINITY; bt[r] = 0; }

    #pragma unroll 4
    for (int tt = 0; tt < KCHUNK / 32; ++tt) {
        const unsigned short* bp = cstream + tt * 1536;
        short8 b0 = ld8(bp);
        short8 b1 = ld8(bp + 512);
        short8 b2 = ld8(bp + 1024);
        float bneg = ql[tt * 32 + c31];
        f32x16 acc;
        #pragma unroll
        for (int r = 0; r < 16; ++r) acc[r] = bneg;
        acc = __builtin_amdgcn_mfma_f32_32x32x16_bf16(a0, b0, acc, 0, 0, 0);
        acc = __builtin_amdgcn_mfma_f32_32x32x16_bf16(a1, b1, acc, 0, 0, 0);
        acc = __builtin_amdgcn_mfma_f32_32x32x16_bf16(a1, b0, acc, 0, 0, 0);
        acc = __builtin_amdgcn_mfma_f32_32x32x16_bf16(a0, b1, acc, 0, 0, 0);
        acc = __builtin_amdgcn_mfma_f32_32x32x16_bf16(a2, b0, acc, 0, 0, 0);
        acc = __builtin_amdgcn_mfma_f32_32x32x16_bf16(a0, b2, acc, 0, 0, 0);
        #pragma unroll
        for (int r = 0; r < 16; ++r)
            if (acc[r] > best[r]) { best[r] = acc[r]; bt[r] = tt; }
    }

    // reconstruct full codes, then reduce over the 32 codes in each half
    int bi[16];
    #pragma unroll
    for (int r = 0; r < 16; ++r) bi[r] = kbase + bt[r] * 32 + c31;

    #pragma unroll
    for (int mask = 1; mask < 32; mask <<= 1) {
        #pragma unroll
        for (int r = 0; r < 16; ++r) {
            float s2 = __shfl_xor(best[r], mask, 64);
            int   i2 = __shfl_xor(bi[r], mask, 64);
            if (s2 > best[r] || (s2 == best[r] && i2 < bi[r])) {
                best[r] = s2; bi[r] = i2;
            }
        }
    }
    if (c31 == 0) {
        #pragma unroll
        for (int r = 0; r < 16; ++r) {
            int row = rt * 32 + (r & 3) + 8 * (r >> 2) + 4 * half;
            pbest[(size_t)row * NCHUNK + blockIdx.y] = best[r];
            pidx [(size_t)row * NCHUNK + blockIdx.y] = bi[r];
        }
    }
}

// -------------------------------------------------------------------------
// merge: fold 16 partials/row; ascending chunk order + strict '>' keeps the
// earliest winner -> matches np first-min argmin.
// -------------------------------------------------------------------------
__global__ __launch_bounds__(256) void merge_argmin(const float* __restrict__ pbest,
                                                    const int* __restrict__ pidx,
                                                    int* __restrict__ out)
{
    const long row = (long)blockIdx.x * 256 + threadIdx.x;
    float best = -INFINITY;
    int   bi   = 0;
    #pragma unroll
    for (int i = 0; i < NCHUNK; ++i) {
        float s = pbest[row * NCHUNK + i];
        if (s > best) { best = s; bi = pidx[row * NCHUNK + i]; }
    }
    out[row] = bi;
}

// -------------------------------------------------------------------------
extern "C" void kernel_launch(void* const* d_in, const int* in_sizes, int n_in,
                              void* d_out, int out_size, void* d_ws, size_t ws_size,
                              hipStream_t stream)
{
    const float* x  = (const float*)d_in[0];   // 8*2048*1024
    const float* W  = (const float*)d_in[1];   // 16*1024
    const float* cb = (const float*)d_in[2];   // 8192*16
    int* out = (int*)d_out;                    // 16384 int32

    char* ws = (char*)d_ws;
    unsigned short* zp  = (unsigned short*)ws;               // 1.5 MB
    unsigned short* cbp = (unsigned short*)(ws + 0x180000);  // 768 KB
    float* nhc  = (float*)(ws + 0x240000);                   // 32 KB
    unsigned short* wb = (unsigned short*)(ws + 0x248000);   // 96 KB
    float* pbest = (float*)(ws + 0x260000);                  // 1 MB
    int*   pidx  = (int*)  (ws + 0x360000);                  // 1 MB

    pack_all<<<56, 256, 0, stream>>>(W, cb, wb, cbp, nhc);
    proj_ln <<<ROWS / 16, 256, 0, stream>>>(x, wb, zp);
    dist_argmin<<<dim3(ROWS / 512, NCHUNK), 1024, 0, stream>>>(zp, cbp, nhc, pbest, pidx);
    merge_argmin<<<ROWS / 256, 256, 0, stream>>>(pbest, pidx, out);
}

// Round 5
// 161.327 us; speedup vs baseline: 11.6104x; 11.6104x over previous
//
#include <hip/hip_runtime.h>
#include <math.h>

#define D      1024
#define CD     16
#define CS     8192
#define ROWS   16384   // B*L
#define LN_EPS 1e-5f
#define KCHUNK 256            // codes per dist chunk (25KB LDS -> 4 blocks/CU)
#define NCHUNK (CS / KCHUNK)  // 32

typedef __attribute__((ext_vector_type(8))) short short8;
typedef __attribute__((ext_vector_type(4))) float f32x4;
typedef __attribute__((ext_vector_type(16))) float f32x16;

__device__ inline unsigned short bf16_rne(float v) {
    unsigned u = __float_as_uint(v);
    unsigned r = u + 0x7FFFu + ((u >> 16) & 1u);
    return (unsigned short)(r >> 16);
}
__device__ inline short8 ld8(const unsigned short* p) { return *(const short8*)p; }

// exact 3-term bf16 split: v = a + b + c, dropped residual ~2^-27 rel
__device__ inline void split3(float v, unsigned short& a, unsigned short& b, unsigned short& c) {
    unsigned u = __float_as_uint(v);
    unsigned r = u + 0x7FFFu + ((u >> 16) & 1u);
    a = (unsigned short)(r >> 16);
    float r1 = v - __uint_as_float(r & 0xFFFF0000u);     // exact
    unsigned u1 = __float_as_uint(r1);
    unsigned r1b = u1 + 0x7FFFu + ((u1 >> 16) & 1u);
    b = (unsigned short)(r1b >> 16);
    float r2 = r1 - __uint_as_float(r1b & 0xFFFF0000u);  // exact
    c = bf16_rne(r2);
}

// -------------------------------------------------------------------------
// pack: blockIdx < 32 -> codebook 3-term split written in 32x32x16 MFMA
//       B-frag STREAM order (tt is now a 256-code-chunk-local tile index):
//       code k: ci=k>>8, tt=(k>>5)&7, c31=k&31;
//       cbp[ci*12288 + tt*1536 + term*512 + (h*32+c31)*8 + j] = term(cd=h*8+j)
//       plus nhc[k] = -0.5||c||^2.
//       blockIdx >= 32 -> W 3-term split in 16x16x32 MFMA-B-frag stream
//       order for proj_ln (unchanged).
// -------------------------------------------------------------------------
__global__ __launch_bounds__(256) void pack_all(const float* __restrict__ W,
                                                const float* __restrict__ cb,
                                                unsigned short* __restrict__ wb,
                                                unsigned short* __restrict__ cbp,
                                                float* __restrict__ nhc)
{
    const int t = threadIdx.x;
    if (blockIdx.x < 32) {
        int k = blockIdx.x * 256 + t;          // 0..8191
        const float* c = cb + (long)k * CD;
        int ci  = k >> 8;         // chunk index (0..31)
        int tt  = (k >> 5) & 7;   // 32-code tile within chunk
        int c31 = k & 31;
        unsigned short* base = cbp + (size_t)ci * 12288 + tt * 1536;
        float csq = 0.f;
        unsigned short h0[16], h1[16], h2[16];
        #pragma unroll
        for (int d = 0; d < 16; ++d) {
            float v = c[d];
            csq = fmaf(v, v, csq);
            split3(v, h0[d], h1[d], h2[d]);
        }
        #pragma unroll
        for (int h = 0; h < 2; ++h) {
            short8 v0, v1, v2;
            #pragma unroll
            for (int j = 0; j < 8; ++j) {
                v0[j] = (short)h0[h * 8 + j];
                v1[j] = (short)h1[h * 8 + j];
                v2[j] = (short)h2[h * 8 + j];
            }
            int lofs = (h * 32 + c31) * 8;
            *(short8*)(base + lofs)        = v0;
            *(short8*)(base + 512 + lofs)  = v1;
            *(short8*)(base + 1024 + lofs) = v2;
        }
        nhc[k] = -0.5f * csq;
    } else {
        int tid = (blockIdx.x - 32) * 256 + t; // 0..6143
        int gk   = tid / 192;
        int rem  = tid % 192;
        int term = rem >> 6;
        int L    = rem & 63;
        int n = L & 15, q = L >> 4;
        const float* src = W + n * D + gk * 32 + q * 8;
        unsigned short* dst = wb + (size_t)tid * 8;
        #pragma unroll
        for (int j = 0; j < 8; ++j) {
            unsigned short h0, h1, h2;
            split3(src[j], h0, h1, h2);
            dst[j] = term == 0 ? h0 : (term == 1 ? h1 : h2);
        }
    }
}

// -------------------------------------------------------------------------
// proj_ln: z = LayerNorm(x @ W^T) fused, emitted as 3-term bf16 split.
// (unchanged from rounds 0-4; near the x-read memory floor)
// -------------------------------------------------------------------------
__global__ __launch_bounds__(256, 4) void proj_ln(const float* __restrict__ x,
                                                  const unsigned short* __restrict__ wb,
                                                  unsigned short* __restrict__ zp)
{
    __shared__ float part[3][64][4];   // waves 1..3 deposit here
    const int t = threadIdx.x;
    const int L = t & 63;
    const int kq = t >> 6;             // K-quarter
    const int rt = blockIdx.x;         // row-tile
    const int n = L & 15, q = L >> 4;

    const float* xrow = x + (size_t)(rt * 16 + n) * D + kq * 256 + q * 8;
    const unsigned short* wbase = wb + (size_t)(kq * 8) * 1536;

    f32x4 acc0 = {0.f, 0.f, 0.f, 0.f};
    f32x4 acc1 = {0.f, 0.f, 0.f, 0.f};
    #pragma unroll
    for (int kk = 0; kk < 8; ++kk) {
        float4 xa = *(const float4*)(xrow + kk * 32);
        float4 xb = *(const float4*)(xrow + kk * 32 + 4);
        const unsigned short* wp = wbase + (size_t)kk * 1536 + L * 8;
        short8 w0 = ld8(wp);
        short8 w1 = ld8(wp + 512);
        short8 w2 = ld8(wp + 1024);
        float vs[8] = {xa.x, xa.y, xa.z, xa.w, xb.x, xb.y, xb.z, xb.w};
        short8 x0, x1, x2;
        #pragma unroll
        for (int j = 0; j < 8; ++j) {
            unsigned short h0, h1, h2;
            split3(vs[j], h0, h1, h2);
            x0[j] = (short)h0; x1[j] = (short)h1; x2[j] = (short)h2;
        }
        // two independent chains (exact products >= 2^-24 kept on each)
        acc0 = __builtin_amdgcn_mfma_f32_16x16x32_bf16(x0, w0, acc0, 0, 0, 0);
        acc1 = __builtin_amdgcn_mfma_f32_16x16x32_bf16(x0, w1, acc1, 0, 0, 0);
        acc0 = __builtin_amdgcn_mfma_f32_16x16x32_bf16(x1, w0, acc0, 0, 0, 0);
        acc1 = __builtin_amdgcn_mfma_f32_16x16x32_bf16(x1, w1, acc1, 0, 0, 0);
        acc0 = __builtin_amdgcn_mfma_f32_16x16x32_bf16(x0, w2, acc0, 0, 0, 0);
        acc1 = __builtin_amdgcn_mfma_f32_16x16x32_bf16(x2, w0, acc1, 0, 0, 0);
    }

    if (kq != 0) {
        #pragma unroll
        for (int r = 0; r < 4; ++r) part[kq - 1][L][r] = acc0[r] + acc1[r];
    }
    __syncthreads();
    if (kq == 0) {
        // C/D layout: col n = channel (lane&15), row = q*4 + r
        #pragma unroll
        for (int r = 0; r < 4; ++r) {
            float zv = acc0[r] + acc1[r] + part[0][L][r] + part[1][L][r] + part[2][L][r];
            float s = zv;
            for (int m = 1; m < 16; m <<= 1) s += __shfl_xor(s, m, 64);
            float mu = s * (1.f / 16.f);
            float dd = zv - mu;
            float v2 = dd * dd;
            for (int m = 1; m < 16; m <<= 1) v2 += __shfl_xor(v2, m, 64);
            float var = v2 * (1.f / 16.f);
            float zn = dd / sqrtf(var + LN_EPS);
            unsigned short h0, h1, h2;
            split3(zn, h0, h1, h2);
            unsigned short* zr = zp + (size_t)(rt * 16 + q * 4 + r) * 48;
            zr[n] = h0; zr[16 + n] = h1; zr[32 + n] = h2;
        }
    }
}

// -------------------------------------------------------------------------
// dist_argmin: score = z.c - 0.5||c||^2 (argmin d2 == argmax score).
// 32x32x16 MFMA + linear LDS staging of the stream-order chunk (conflict-
// free, round 3). Round-5 change: KCHUNK 512->256 so LDS = 25KB/block and
// 4 blocks x 8 waves = 32 waves/CU are resident (round 3: 50KB -> 3 blocks
// -> 34.6% occupancy + tail). Grid 64x32 = 2048 blocks = exactly 2 clean
// generations at 4 blocks/CU. Inner loop byte-identical to rounds 3-4
// (absmax 0.0). __launch_bounds__(512,4) keeps the 128-VGPR ceiling
// (round-4 lesson: (1024,8)'s 64-cap spilled acc to scratch, 6.2GB HBM).
// A: m=lane&31 (z row), k=(lane>>5)*8+j. B: n=lane&31 (code), same k.
// C/D: col=lane&31, row=(reg&3)+8*(reg>>2)+4*(lane>>5). Bias enters as the
// C operand of the 1st MFMA; winner tracked as 3-bit tt, full code
// reconstructed once before the cross-lane reduce.
// -------------------------------------------------------------------------
__global__ __launch_bounds__(512, 4) void dist_argmin(const unsigned short* __restrict__ zp,
                                                      const unsigned short* __restrict__ cbp,
                                                      const float* __restrict__ nhc,
                                                      float* __restrict__ pbest,
                                                      int* __restrict__ pidx)
{
    __shared__ __align__(16) unsigned short cl[KCHUNK * 48];  // 24 KB, stream order
    __shared__ float ql[KCHUNK];                              // 1 KB
    const int t = threadIdx.x;
    const int kbase = blockIdx.y * KCHUNK;

    {   // linear stage preserves stream order: 24KB / (512 thr * 16B) = 3 iters
        float4* dst = (float4*)cl;
        const float4* src = (const float4*)(cbp + (size_t)kbase * 48);
        #pragma unroll
        for (int i = 0; i < 3; ++i) dst[t + i * 512] = src[t + i * 512];
        if (t < KCHUNK / 4) ((float4*)ql)[t] = ((const float4*)(nhc + kbase))[t];
    }
    __syncthreads();

    const int L = t & 63;
    const int w = t >> 6;      // wave 0..7
    const int c31 = L & 31;    // code col (B n) / z row (A m)
    const int half = L >> 5;   // k-half selector

    const int rt = blockIdx.x * 8 + w;   // 32-row tile index (512 total)
    const unsigned short* zr = zp + (size_t)(rt * 32 + c31) * 48 + half * 8;
    short8 a0 = ld8(zr);        // z term-0 fragment
    short8 a1 = ld8(zr + 16);   // z term-1
    short8 a2 = ld8(zr + 32);   // z term-2

    const unsigned short* cstream = cl + L * 8;  // lane base; tt/term are imm offsets

    float best[16];
    int   bt[16];
    #pragma unroll
    for (int r = 0; r < 16; ++r) { best[r] = -INFINITY; bt[r] = 0; }

    #pragma unroll
    for (int tt = 0; tt < KCHUNK / 32; ++tt) {
        const unsigned short* bp = cstream + tt * 1536;
        short8 b0 = ld8(bp);
        short8 b1 = ld8(bp + 512);
        short8 b2 = ld8(bp + 1024);
        float bneg = ql[tt * 32 + c31];
        f32x16 acc;
        #pragma unroll
        for (int r = 0; r < 16; ++r) acc[r] = bneg;
        acc = __builtin_amdgcn_mfma_f32_32x32x16_bf16(a0, b0, acc, 0, 0, 0);
        acc = __builtin_amdgcn_mfma_f32_32x32x16_bf16(a1, b1, acc, 0, 0, 0);
        acc = __builtin_amdgcn_mfma_f32_32x32x16_bf16(a1, b0, acc, 0, 0, 0);
        acc = __builtin_amdgcn_mfma_f32_32x32x16_bf16(a0, b1, acc, 0, 0, 0);
        acc = __builtin_amdgcn_mfma_f32_32x32x16_bf16(a2, b0, acc, 0, 0, 0);
        acc = __builtin_amdgcn_mfma_f32_32x32x16_bf16(a0, b2, acc, 0, 0, 0);
        #pragma unroll
        for (int r = 0; r < 16; ++r)
            if (acc[r] > best[r]) { best[r] = acc[r]; bt[r] = tt; }
    }

    // reconstruct full codes, then reduce over the 32 codes in each half
    int bi[16];
    #pragma unroll
    for (int r = 0; r < 16; ++r) bi[r] = kbase + bt[r] * 32 + c31;

    #pragma unroll
    for (int mask = 1; mask < 32; mask <<= 1) {
        #pragma unroll
        for (int r = 0; r < 16; ++r) {
            float s2 = __shfl_xor(best[r], mask, 64);
            int   i2 = __shfl_xor(bi[r], mask, 64);
            if (s2 > best[r] || (s2 == best[r] && i2 < bi[r])) {
                best[r] = s2; bi[r] = i2;
            }
        }
    }
    if (c31 == 0) {
        #pragma unroll
        for (int r = 0; r < 16; ++r) {
            int row = rt * 32 + (r & 3) + 8 * (r >> 2) + 4 * half;
            pbest[(size_t)row * NCHUNK + blockIdx.y] = best[r];
            pidx [(size_t)row * NCHUNK + blockIdx.y] = bi[r];
        }
    }
}

// -------------------------------------------------------------------------
// merge: fold 32 partials/row; ascending chunk order + strict '>' keeps the
// earliest winner -> matches np first-min argmin.
// -------------------------------------------------------------------------
__global__ __launch_bounds__(256) void merge_argmin(const float* __restrict__ pbest,
                                                    const int* __restrict__ pidx,
                                                    int* __restrict__ out)
{
    const long row = (long)blockIdx.x * 256 + threadIdx.x;
    float best = -INFINITY;
    int   bi   = 0;
    #pragma unroll
    for (int i = 0; i < NCHUNK; ++i) {
        float s = pbest[row * NCHUNK + i];
        if (s > best) { best = s; bi = pidx[row * NCHUNK + i]; }
    }
    out[row] = bi;
}

// -------------------------------------------------------------------------
extern "C" void kernel_launch(void* const* d_in, const int* in_sizes, int n_in,
                              void* d_out, int out_size, void* d_ws, size_t ws_size,
                              hipStream_t stream)
{
    const float* x  = (const float*)d_in[0];   // 8*2048*1024
    const float* W  = (const float*)d_in[1];   // 16*1024
    const float* cb = (const float*)d_in[2];   // 8192*16
    int* out = (int*)d_out;                    // 16384 int32

    char* ws = (char*)d_ws;
    unsigned short* zp  = (unsigned short*)ws;               // 1.5 MB
    unsigned short* cbp = (unsigned short*)(ws + 0x180000);  // 768 KB
    float* nhc  = (float*)(ws + 0x240000);                   // 32 KB
    unsigned short* wb = (unsigned short*)(ws + 0x248000);   // 96 KB
    float* pbest = (float*)(ws + 0x260000);                  // 2 MB (ROWS*32*4)
    int*   pidx  = (int*)  (ws + 0x460000);                  // 2 MB

    pack_all<<<56, 256, 0, stream>>>(W, cb, wb, cbp, nhc);
    proj_ln <<<ROWS / 16, 256, 0, stream>>>(x, wb, zp);
    dist_argmin<<<dim3(ROWS / 256, NCHUNK), 512, 0, stream>>>(zp, cbp, nhc, pbest, pidx);
    merge_argmin<<<ROWS / 256, 256, 0, stream>>>(pbest, pidx, out);
}

// Round 6
// 152.156 us; speedup vs baseline: 12.3102x; 1.0603x over previous
//
#include <hip/hip_runtime.h>
#include <math.h>

#define D      1024
#define CD     16
#define CS     8192
#define ROWS   16384   // B*L
#define LN_EPS 1e-5f
#define KCHUNK 512            // codes per dist chunk
#define NCHUNK (CS / KCHUNK)  // 16

typedef __attribute__((ext_vector_type(8))) short short8;
typedef __attribute__((ext_vector_type(4))) float f32x4;
typedef __attribute__((ext_vector_type(16))) float f32x16;

__device__ inline unsigned short bf16_rne(float v) {
    unsigned u = __float_as_uint(v);
    unsigned r = u + 0x7FFFu + ((u >> 16) & 1u);
    return (unsigned short)(r >> 16);
}
__device__ inline short8 ld8(const unsigned short* p) { return *(const short8*)p; }

// exact 3-term bf16 split: v = a + b + c, dropped residual ~2^-27 rel
__device__ inline void split3(float v, unsigned short& a, unsigned short& b, unsigned short& c) {
    unsigned u = __float_as_uint(v);
    unsigned r = u + 0x7FFFu + ((u >> 16) & 1u);
    a = (unsigned short)(r >> 16);
    float r1 = v - __uint_as_float(r & 0xFFFF0000u);     // exact
    unsigned u1 = __float_as_uint(r1);
    unsigned r1b = u1 + 0x7FFFu + ((u1 >> 16) & 1u);
    b = (unsigned short)(r1b >> 16);
    float r2 = r1 - __uint_as_float(r1b & 0xFFFF0000u);  // exact
    c = bf16_rne(r2);
}

// -------------------------------------------------------------------------
// pack: blockIdx < 32 -> codebook 3-term split written in 32x32x16 MFMA
//       B-frag STREAM order (round-3 layout, verified):
//       code k: ci=k>>9, tt=(k>>5)&15, c31=k&31;
//       cbp[ci*24576 + tt*1536 + term*512 + (h*32+c31)*8 + j] = term(cd=h*8+j)
//       plus nhc[k] = -0.5||c||^2.
//       blockIdx >= 32 -> W 3-term split in 16x16x32 MFMA-B-frag stream
//       order for proj_ln (unchanged).
// -------------------------------------------------------------------------
__global__ __launch_bounds__(256) void pack_all(const float* __restrict__ W,
                                                const float* __restrict__ cb,
                                                unsigned short* __restrict__ wb,
                                                unsigned short* __restrict__ cbp,
                                                float* __restrict__ nhc)
{
    const int t = threadIdx.x;
    if (blockIdx.x < 32) {
        int k = blockIdx.x * 256 + t;          // 0..8191
        const float* c = cb + (long)k * CD;
        int ci  = k >> 9;
        int tt  = (k >> 5) & 15;
        int c31 = k & 31;
        unsigned short* base = cbp + (size_t)ci * 24576 + tt * 1536;
        float csq = 0.f;
        unsigned short h0[16], h1[16], h2[16];
        #pragma unroll
        for (int d = 0; d < 16; ++d) {
            float v = c[d];
            csq = fmaf(v, v, csq);
            split3(v, h0[d], h1[d], h2[d]);
        }
        #pragma unroll
        for (int h = 0; h < 2; ++h) {
            short8 v0, v1, v2;
            #pragma unroll
            for (int j = 0; j < 8; ++j) {
                v0[j] = (short)h0[h * 8 + j];
                v1[j] = (short)h1[h * 8 + j];
                v2[j] = (short)h2[h * 8 + j];
            }
            int lofs = (h * 32 + c31) * 8;
            *(short8*)(base + lofs)        = v0;
            *(short8*)(base + 512 + lofs)  = v1;
            *(short8*)(base + 1024 + lofs) = v2;
        }
        nhc[k] = -0.5f * csq;
    } else {
        int tid = (blockIdx.x - 32) * 256 + t; // 0..6143
        int gk   = tid / 192;
        int rem  = tid % 192;
        int term = rem >> 6;
        int L    = rem & 63;
        int n = L & 15, q = L >> 4;
        const float* src = W + n * D + gk * 32 + q * 8;
        unsigned short* dst = wb + (size_t)tid * 8;
        #pragma unroll
        for (int j = 0; j < 8; ++j) {
            unsigned short h0, h1, h2;
            split3(src[j], h0, h1, h2);
            dst[j] = term == 0 ? h0 : (term == 1 ? h1 : h2);
        }
    }
}

// -------------------------------------------------------------------------
// proj_ln: z = LayerNorm(x @ W^T) fused, emitted as 3-term bf16 split.
// (unchanged from rounds 0-5; near the x-read memory floor)
// -------------------------------------------------------------------------
__global__ __launch_bounds__(256, 4) void proj_ln(const float* __restrict__ x,
                                                  const unsigned short* __restrict__ wb,
                                                  unsigned short* __restrict__ zp)
{
    __shared__ float part[3][64][4];   // waves 1..3 deposit here
    const int t = threadIdx.x;
    const int L = t & 63;
    const int kq = t >> 6;             // K-quarter
    const int rt = blockIdx.x;         // row-tile
    const int n = L & 15, q = L >> 4;

    const float* xrow = x + (size_t)(rt * 16 + n) * D + kq * 256 + q * 8;
    const unsigned short* wbase = wb + (size_t)(kq * 8) * 1536;

    f32x4 acc0 = {0.f, 0.f, 0.f, 0.f};
    f32x4 acc1 = {0.f, 0.f, 0.f, 0.f};
    #pragma unroll
    for (int kk = 0; kk < 8; ++kk) {
        float4 xa = *(const float4*)(xrow + kk * 32);
        float4 xb = *(const float4*)(xrow + kk * 32 + 4);
        const unsigned short* wp = wbase + (size_t)kk * 1536 + L * 8;
        short8 w0 = ld8(wp);
        short8 w1 = ld8(wp + 512);
        short8 w2 = ld8(wp + 1024);
        float vs[8] = {xa.x, xa.y, xa.z, xa.w, xb.x, xb.y, xb.z, xb.w};
        short8 x0, x1, x2;
        #pragma unroll
        for (int j = 0; j < 8; ++j) {
            unsigned short h0, h1, h2;
            split3(vs[j], h0, h1, h2);
            x0[j] = (short)h0; x1[j] = (short)h1; x2[j] = (short)h2;
        }
        // two independent chains (exact products >= 2^-24 kept on each)
        acc0 = __builtin_amdgcn_mfma_f32_16x16x32_bf16(x0, w0, acc0, 0, 0, 0);
        acc1 = __builtin_amdgcn_mfma_f32_16x16x32_bf16(x0, w1, acc1, 0, 0, 0);
        acc0 = __builtin_amdgcn_mfma_f32_16x16x32_bf16(x1, w0, acc0, 0, 0, 0);
        acc1 = __builtin_amdgcn_mfma_f32_16x16x32_bf16(x1, w1, acc1, 0, 0, 0);
        acc0 = __builtin_amdgcn_mfma_f32_16x16x32_bf16(x0, w2, acc0, 0, 0, 0);
        acc1 = __builtin_amdgcn_mfma_f32_16x16x32_bf16(x2, w0, acc1, 0, 0, 0);
    }

    if (kq != 0) {
        #pragma unroll
        for (int r = 0; r < 4; ++r) part[kq - 1][L][r] = acc0[r] + acc1[r];
    }
    __syncthreads();
    if (kq == 0) {
        // C/D layout: col n = channel (lane&15), row = q*4 + r
        #pragma unroll
        for (int r = 0; r < 4; ++r) {
            float zv = acc0[r] + acc1[r] + part[0][L][r] + part[1][L][r] + part[2][L][r];
            float s = zv;
            for (int m = 1; m < 16; m <<= 1) s += __shfl_xor(s, m, 64);
            float mu = s * (1.f / 16.f);
            float dd = zv - mu;
            float v2 = dd * dd;
            for (int m = 1; m < 16; m <<= 1) v2 += __shfl_xor(v2, m, 64);
            float var = v2 * (1.f / 16.f);
            float zn = dd / sqrtf(var + LN_EPS);
            unsigned short h0, h1, h2;
            split3(zn, h0, h1, h2);
            unsigned short* zr = zp + (size_t)(rt * 16 + q * 4 + r) * 48;
            zr[n] = h0; zr[16 + n] = h1; zr[32 + n] = h2;
        }
    }
}

// -------------------------------------------------------------------------
// dist_argmin: score = z.c - 0.5||c||^2 (argmin d2 == argmax score).
// Round-3 base (32x32x16, stream-order linear LDS, conflict-free, KCHUNK
// 512, 512 thr, grid 64x16 -- best-measured 32x32 state). Round-6 change:
// the 6 MFMAs per tile are split into TWO INDEPENDENT 3-chains
//   P = bias + z0c0 + z1c0 + z2c0      (bias in C of 1st MFMA)
//   Q =   0  + z1c1 + z0c1 + z0c2      (loop-invariant zero C, hoisted)
// score = P + Q at select time. Serial MFMA latency per tile halves
// (~400 -> ~200cy); the chains interleave issue. Cost: +16 adds/tile.
// Every product is still an exact bf16 x bf16; only the final summation
// tree reorders (<=2 ulp) -- same perturbation class as round 0->1 which
// argmin absorbed at absmax 0.0.
// A: m=lane&31 (z row), k=(lane>>5)*8+j. B: n=lane&31 (code), same k.
// C/D: col=lane&31, row=(reg&3)+8*(reg>>2)+4*(lane>>5).
// -------------------------------------------------------------------------
__global__ __launch_bounds__(512, 4) void dist_argmin(const unsigned short* __restrict__ zp,
                                                      const unsigned short* __restrict__ cbp,
                                                      const float* __restrict__ nhc,
                                                      float* __restrict__ pbest,
                                                      int* __restrict__ pidx)
{
    __shared__ __align__(16) unsigned short cl[KCHUNK * 48];  // 48 KB, stream order
    __shared__ float ql[KCHUNK];                              // 2 KB
    const int t = threadIdx.x;
    const int kbase = blockIdx.y * KCHUNK;

    {   // linear stage preserves stream order
        float4* dst = (float4*)cl;
        const float4* src = (const float4*)(cbp + (size_t)kbase * 48);
        #pragma unroll
        for (int i = 0; i < 6; ++i) dst[t + i * 512] = src[t + i * 512];
        if (t < KCHUNK / 4) ((float4*)ql)[t] = ((const float4*)(nhc + kbase))[t];
    }
    __syncthreads();

    const int L = t & 63;
    const int w = t >> 6;
    const int c31 = L & 31;    // code col (B n) / z row (A m)
    const int half = L >> 5;   // k-half selector

    const int rt = blockIdx.x * 8 + w;   // 32-row tile index (512 total)
    const unsigned short* zr = zp + (size_t)(rt * 32 + c31) * 48 + half * 8;
    short8 a0 = ld8(zr);        // z term-0 fragment
    short8 a1 = ld8(zr + 16);   // z term-1
    short8 a2 = ld8(zr + 32);   // z term-2

    const unsigned short* cstream = cl + L * 8;  // lane base; tt/term are imm offsets

    const f32x16 zeroC = {0.f, 0.f, 0.f, 0.f, 0.f, 0.f, 0.f, 0.f,
                          0.f, 0.f, 0.f, 0.f, 0.f, 0.f, 0.f, 0.f};  // hoisted

    float best[16];
    int   bt[16];
    #pragma unroll
    for (int r = 0; r < 16; ++r) { best[r] = -INFINITY; bt[r] = 0; }

    #pragma unroll 4
    for (int tt = 0; tt < KCHUNK / 32; ++tt) {
        const unsigned short* bp = cstream + tt * 1536;
        short8 b0 = ld8(bp);
        short8 b1 = ld8(bp + 512);
        short8 b2 = ld8(bp + 1024);
        float bneg = ql[tt * 32 + c31];
        f32x16 accP;
        #pragma unroll
        for (int r = 0; r < 16; ++r) accP[r] = bneg;
        f32x16 accQ;
        // two independent 3-deep chains, interleaved issue
        accP = __builtin_amdgcn_mfma_f32_32x32x16_bf16(a0, b0, accP, 0, 0, 0);
        accQ = __builtin_amdgcn_mfma_f32_32x32x16_bf16(a1, b1, zeroC, 0, 0, 0);
        accP = __builtin_amdgcn_mfma_f32_32x32x16_bf16(a1, b0, accP, 0, 0, 0);
        accQ = __builtin_amdgcn_mfma_f32_32x32x16_bf16(a0, b1, accQ, 0, 0, 0);
        accP = __builtin_amdgcn_mfma_f32_32x32x16_bf16(a2, b0, accP, 0, 0, 0);
        accQ = __builtin_amdgcn_mfma_f32_32x32x16_bf16(a0, b2, accQ, 0, 0, 0);
        #pragma unroll
        for (int r = 0; r < 16; ++r) {
            float s = accP[r] + accQ[r];
            if (s > best[r]) { best[r] = s; bt[r] = tt; }
        }
    }

    // reconstruct full codes, then reduce over the 32 codes in each half
    int bi[16];
    #pragma unroll
    for (int r = 0; r < 16; ++r) bi[r] = kbase + bt[r] * 32 + c31;

    #pragma unroll
    for (int mask = 1; mask < 32; mask <<= 1) {
        #pragma unroll
        for (int r = 0; r < 16; ++r) {
            float s2 = __shfl_xor(best[r], mask, 64);
            int   i2 = __shfl_xor(bi[r], mask, 64);
            if (s2 > best[r] || (s2 == best[r] && i2 < bi[r])) {
                best[r] = s2; bi[r] = i2;
            }
        }
    }
    if (c31 == 0) {
        #pragma unroll
        for (int r = 0; r < 16; ++r) {
            int row = rt * 32 + (r & 3) + 8 * (r >> 2) + 4 * half;
            pbest[(size_t)row * NCHUNK + blockIdx.y] = best[r];
            pidx [(size_t)row * NCHUNK + blockIdx.y] = bi[r];
        }
    }
}

// -------------------------------------------------------------------------
// merge: fold 16 partials/row; ascending chunk order + strict '>' keeps the
// earliest winner -> matches np first-min argmin.
// -------------------------------------------------------------------------
__global__ __launch_bounds__(256) void merge_argmin(const float* __restrict__ pbest,
                                                    const int* __restrict__ pidx,
                                                    int* __restrict__ out)
{
    const long row = (long)blockIdx.x * 256 + threadIdx.x;
    float best = -INFINITY;
    int   bi   = 0;
    #pragma unroll
    for (int i = 0; i < NCHUNK; ++i) {
        float s = pbest[row * NCHUNK + i];
        if (s > best) { best = s; bi = pidx[row * NCHUNK + i]; }
    }
    out[row] = bi;
}

// -------------------------------------------------------------------------
extern "C" void kernel_launch(void* const* d_in, const int* in_sizes, int n_in,
                              void* d_out, int out_size, void* d_ws, size_t ws_size,
                              hipStream_t stream)
{
    const float* x  = (const float*)d_in[0];   // 8*2048*1024
    const float* W  = (const float*)d_in[1];   // 16*1024
    const float* cb = (const float*)d_in[2];   // 8192*16
    int* out = (int*)d_out;                    // 16384 int32

    char* ws = (char*)d_ws;
    unsigned short* zp  = (unsigned short*)ws;               // 1.5 MB
    unsigned short* cbp = (unsigned short*)(ws + 0x180000);  // 768 KB
    float* nhc  = (float*)(ws + 0x240000);                   // 32 KB
    unsigned short* wb = (unsigned short*)(ws + 0x248000);   // 96 KB
    float* pbest = (float*)(ws + 0x260000);                  // 1 MB
    int*   pidx  = (int*)  (ws + 0x360000);                  // 1 MB

    pack_all<<<56, 256, 0, stream>>>(W, cb, wb, cbp, nhc);
    proj_ln <<<ROWS / 16, 256, 0, stream>>>(x, wb, zp);
    dist_argmin<<<dim3(ROWS / 256, NCHUNK), 512, 0, stream>>>(zp, cbp, nhc, pbest, pidx);
    merge_argmin<<<ROWS / 256, 256, 0, stream>>>(pbest, pidx, out);
}

// Round 8
// 138.620 us; speedup vs baseline: 13.5123x; 1.0976x over previous
//
#include <hip/hip_runtime.h>
#include <math.h>

#define D      1024
#define CD     16
#define CS     8192
#define ROWS   16384   // B*L
#define LN_EPS 1e-5f
#define KCHUNK 512            // codes per dist chunk
#define NCHUNK (CS / KCHUNK)  // 16

typedef __attribute__((ext_vector_type(8))) short short8;
typedef __attribute__((ext_vector_type(4))) float f32x4;

__device__ inline unsigned short bf16_rne(float v) {
    unsigned u = __float_as_uint(v);
    unsigned r = u + 0x7FFFu + ((u >> 16) & 1u);
    return (unsigned short)(r >> 16);
}
__device__ inline short8 ld8(const unsigned short* p) { return *(const short8*)p; }

// exact 3-term bf16 split: v = a + b + c, dropped residual ~2^-27 rel
__device__ inline void split3(float v, unsigned short& a, unsigned short& b, unsigned short& c) {
    unsigned u = __float_as_uint(v);
    unsigned r = u + 0x7FFFu + ((u >> 16) & 1u);
    a = (unsigned short)(r >> 16);
    float r1 = v - __uint_as_float(r & 0xFFFF0000u);     // exact
    unsigned u1 = __float_as_uint(r1);
    unsigned r1b = u1 + 0x7FFFu + ((u1 >> 16) & 1u);
    b = (unsigned short)(r1b >> 16);
    float r2 = r1 - __uint_as_float(r1b & 0xFFFF0000u);  // exact
    c = bf16_rne(r2);
}

// -------------------------------------------------------------------------
// pack: blockIdx < 32 -> codebook 3-term split in 16x16 MFMA B-frag STREAM
//       order, COMPACT: 768 shorts (1.5KB) per 16-code tile, no holes
//       (round-7 bug: 1536 stride left half the chunk unstaged):
//         S1 [0..511]:   S1[(q*16+n)*8+i], q=0: t0[0..7], q=1: t0[8..15],
//                                          q=2: t1[0..7], q=3: t1[8..15]
//         S3h[512..767]: S3h[(h*16+n)*8+i] = t2[h*8+i]
//       plus nhc[k] = -0.5||c||^2.
//       blockIdx >= 32 -> W 3-term split in 16x16x32 MFMA-B-frag stream
//       order for proj_ln (unchanged, rounds 0-7).
// -------------------------------------------------------------------------
__global__ __launch_bounds__(256) void pack_all(const float* __restrict__ W,
                                                const float* __restrict__ cb,
                                                unsigned short* __restrict__ wb,
                                                unsigned short* __restrict__ cbp,
                                                float* __restrict__ nhc)
{
    const int t = threadIdx.x;
    if (blockIdx.x < 32) {
        int k = blockIdx.x * 256 + t;          // 0..8191
        const float* c = cb + (long)k * CD;
        int tile = k >> 4;
        int n    = k & 15;
        unsigned short* base = cbp + (size_t)tile * 768;
        float csq = 0.f;
        unsigned short h0[16], h1[16], h2[16];
        #pragma unroll
        for (int d = 0; d < 16; ++d) {
            float v = c[d];
            csq = fmaf(v, v, csq);
            split3(v, h0[d], h1[d], h2[d]);
        }
        #pragma unroll
        for (int qq = 0; qq < 4; ++qq) {
            const unsigned short* src = (qq < 2 ? h0 : h1) + (qq & 1) * 8;
            short8 v;
            #pragma unroll
            for (int j = 0; j < 8; ++j) v[j] = (short)src[j];
            *(short8*)(base + qq * 128 + n * 8) = v;
        }
        #pragma unroll
        for (int h = 0; h < 2; ++h) {
            short8 v;
            #pragma unroll
            for (int j = 0; j < 8; ++j) v[j] = (short)h2[h * 8 + j];
            *(short8*)(base + 512 + h * 128 + n * 8) = v;
        }
        nhc[k] = -0.5f * csq;
    } else {
        int tid = (blockIdx.x - 32) * 256 + t; // 0..6143
        int gk   = tid / 192;
        int rem  = tid % 192;
        int term = rem >> 6;
        int L    = rem & 63;
        int n = L & 15, q = L >> 4;
        const float* src = W + n * D + gk * 32 + q * 8;
        unsigned short* dst = wb + (size_t)tid * 8;
        #pragma unroll
        for (int j = 0; j < 8; ++j) {
            unsigned short h0, h1, h2;
            split3(src[j], h0, h1, h2);
            dst[j] = term == 0 ? h0 : (term == 1 ? h1 : h2);
        }
    }
}

// -------------------------------------------------------------------------
// proj_ln: z = LayerNorm(x @ W^T) fused, emitted as 3-term bf16 split.
// (unchanged from rounds 0-7; near the x-read memory floor)
// -------------------------------------------------------------------------
__global__ __launch_bounds__(256, 4) void proj_ln(const float* __restrict__ x,
                                                  const unsigned short* __restrict__ wb,
                                                  unsigned short* __restrict__ zp)
{
    __shared__ float part[3][64][4];   // waves 1..3 deposit here
    const int t = threadIdx.x;
    const int L = t & 63;
    const int kq = t >> 6;             // K-quarter
    const int rt = blockIdx.x;         // row-tile
    const int n = L & 15, q = L >> 4;

    const float* xrow = x + (size_t)(rt * 16 + n) * D + kq * 256 + q * 8;
    const unsigned short* wbase = wb + (size_t)(kq * 8) * 1536;

    f32x4 acc0 = {0.f, 0.f, 0.f, 0.f};
    f32x4 acc1 = {0.f, 0.f, 0.f, 0.f};
    #pragma unroll
    for (int kk = 0; kk < 8; ++kk) {
        float4 xa = *(const float4*)(xrow + kk * 32);
        float4 xb = *(const float4*)(xrow + kk * 32 + 4);
        const unsigned short* wp = wbase + (size_t)kk * 1536 + L * 8;
        short8 w0 = ld8(wp);
        short8 w1 = ld8(wp + 512);
        short8 w2 = ld8(wp + 1024);
        float vs[8] = {xa.x, xa.y, xa.z, xa.w, xb.x, xb.y, xb.z, xb.w};
        short8 x0, x1, x2;
        #pragma unroll
        for (int j = 0; j < 8; ++j) {
            unsigned short h0, h1, h2;
            split3(vs[j], h0, h1, h2);
            x0[j] = (short)h0; x1[j] = (short)h1; x2[j] = (short)h2;
        }
        // two independent chains (exact products >= 2^-24 kept on each)
        acc0 = __builtin_amdgcn_mfma_f32_16x16x32_bf16(x0, w0, acc0, 0, 0, 0);
        acc1 = __builtin_amdgcn_mfma_f32_16x16x32_bf16(x0, w1, acc1, 0, 0, 0);
        acc0 = __builtin_amdgcn_mfma_f32_16x16x32_bf16(x1, w0, acc0, 0, 0, 0);
        acc1 = __builtin_amdgcn_mfma_f32_16x16x32_bf16(x1, w1, acc1, 0, 0, 0);
        acc0 = __builtin_amdgcn_mfma_f32_16x16x32_bf16(x0, w2, acc0, 0, 0, 0);
        acc1 = __builtin_amdgcn_mfma_f32_16x16x32_bf16(x2, w0, acc1, 0, 0, 0);
    }

    if (kq != 0) {
        #pragma unroll
        for (int r = 0; r < 4; ++r) part[kq - 1][L][r] = acc0[r] + acc1[r];
    }
    __syncthreads();
    if (kq == 0) {
        // C/D layout: col n = channel (lane&15), row = q*4 + r
        #pragma unroll
        for (int r = 0; r < 4; ++r) {
            float zv = acc0[r] + acc1[r] + part[0][L][r] + part[1][L][r] + part[2][L][r];
            float s = zv;
            for (int m = 1; m < 16; m <<= 1) s += __shfl_xor(s, m, 64);
            float mu = s * (1.f / 16.f);
            float dd = zv - mu;
            float v2 = dd * dd;
            for (int m = 1; m < 16; m <<= 1) v2 += __shfl_xor(v2, m, 64);
            float var = v2 * (1.f / 16.f);
            float zn = dd / sqrtf(var + LN_EPS);
            unsigned short h0, h1, h2;
            split3(zn, h0, h1, h2);
            unsigned short* zr = zp + (size_t)(rt * 16 + q * 4 + r) * 48;
            zr[n] = h0; zr[16 + n] = h1; zr[32 + n] = h2;
        }
    }
}

// -------------------------------------------------------------------------
// dist_argmin: score = z.c - 0.5||c||^2 (argmin d2 == argmax score).
// ROUND-0 STRUCTURE (best measured: 16x16x32, j=2 row-tiles/wave, half-swap
// exact 6-product split, bias-as-C, 3 MFMAs/tile x 2 independent chains),
// with ONE change vs round 0: cbp/LDS in COMPACT B-frag stream order
// (768 shorts/tile), so the two in-loop LDS reads are lane-contiguous:
//   b1 = ld8(cl + tt*768 + L*8)                  (1KB contiguous/wave)
//   b3 = ld8(cl + tt*768 + L*8 + (L>=32?256:0))  (two contiguous 512B)
// Round-0's layout had 4-way bank conflicts on both (bank=(24n+4q)%32,
// ~1.58x tax, m136 class); round 3 measured this read pattern at 0
// conflicts. Scores bit-identical to round 0 (same fragments, same MFMA
// order). LDS total 50KB = round 0's footprint; occupancy unchanged.
// -------------------------------------------------------------------------
__global__ __launch_bounds__(512, 4) void dist_argmin(const unsigned short* __restrict__ zp,
                                                      const unsigned short* __restrict__ cbp,
                                                      const float* __restrict__ nhc,
                                                      float* __restrict__ pbest,
                                                      int* __restrict__ pidx)
{
    __shared__ __align__(16) unsigned short cl[KCHUNK * 48];  // 48 KB compact stream order
    __shared__ float ql[KCHUNK];                              // 2 KB
    const int t = threadIdx.x;
    const int kbase = blockIdx.y * KCHUNK;

    {   // linear stage preserves stream order: 48KB / (512 thr * 16B) = 6 iters
        float4* dst = (float4*)cl;
        const float4* src = (const float4*)(cbp + (size_t)kbase * 48);
        #pragma unroll
        for (int i = 0; i < 6; ++i) dst[t + i * 512] = src[t + i * 512];
        if (t < KCHUNK / 4) ((float4*)ql)[t] = ((const float4*)(nhc + kbase))[t];
    }
    __syncthreads();

    const int L = t & 63;
    const int w = t >> 6;
    const int n = L & 15;    // code col (B n) / z col in C/D
    const int q = L >> 4;

    const int oa2 = (q * 8 + 16) & 31;                 // [z1|z0]
    const int oa3 = q < 2 ? 32 + q * 8 : (q - 2) * 8;  // [z2|z0]

    short8 a1[2], a2[2], a3[2];
    const int rt0 = blockIdx.x * 16 + w * 2;
    #pragma unroll
    for (int j = 0; j < 2; ++j) {
        const unsigned short* zr = zp + (size_t)((rt0 + j) * 16 + n) * 48;
        a1[j] = ld8(zr + q * 8);
        a2[j] = ld8(zr + oa2);
        a3[j] = ld8(zr + oa3);
    }

    // per-lane stream bases (conflict-free contiguous LDS reads)
    const unsigned short* b1base = cl + L * 8;
    const unsigned short* b3base = cl + L * 8 + (L >= 32 ? 256 : 0);

    float best[2][4];
    int   bt[2][4];
    #pragma unroll
    for (int j = 0; j < 2; ++j)
        #pragma unroll
        for (int r = 0; r < 4; ++r) { best[j][r] = -INFINITY; bt[j][r] = 0; }

    #pragma unroll 2
    for (int tt = 0; tt < KCHUNK / 16; ++tt) {   // 32 tiles of 16 codes
        short8 b1 = ld8(b1base + tt * 768);      // [c0|c1]
        short8 b3 = ld8(b3base + tt * 768);      // [c0|c2]
        float bneg = ql[tt * 16 + n];
        f32x4 bias = {bneg, bneg, bneg, bneg};
        f32x4 acc[2];
        #pragma unroll
        for (int j = 0; j < 2; ++j)
            acc[j] = __builtin_amdgcn_mfma_f32_16x16x32_bf16(a1[j], b1, bias, 0, 0, 0);
        #pragma unroll
        for (int j = 0; j < 2; ++j)
            acc[j] = __builtin_amdgcn_mfma_f32_16x16x32_bf16(a2[j], b1, acc[j], 0, 0, 0);
        #pragma unroll
        for (int j = 0; j < 2; ++j)
            acc[j] = __builtin_amdgcn_mfma_f32_16x16x32_bf16(a3[j], b3, acc[j], 0, 0, 0);
        #pragma unroll
        for (int j = 0; j < 2; ++j)
            #pragma unroll
            for (int r = 0; r < 4; ++r)
                if (acc[j][r] > best[j][r]) { best[j][r] = acc[j][r]; bt[j][r] = tt; }
    }

    // reconstruct full codes, then reduce across the 16 codes (n lanes)
    int bi[2][4];
    #pragma unroll
    for (int j = 0; j < 2; ++j)
        #pragma unroll
        for (int r = 0; r < 4; ++r) bi[j][r] = kbase + bt[j][r] * 16 + n;

    #pragma unroll
    for (int mask = 1; mask < 16; mask <<= 1) {
        #pragma unroll
        for (int j = 0; j < 2; ++j)
            #pragma unroll
            for (int r = 0; r < 4; ++r) {
                float s2 = __shfl_xor(best[j][r], mask, 64);
                int   i2 = __shfl_xor(bi[j][r], mask, 64);
                if (s2 > best[j][r] || (s2 == best[j][r] && i2 < bi[j][r])) {
                    best[j][r] = s2; bi[j][r] = i2;
                }
            }
    }
    if (n == 0) {
        #pragma unroll
        for (int j = 0; j < 2; ++j)
            #pragma unroll
            for (int r = 0; r < 4; ++r) {
                int row = (rt0 + j) * 16 + q * 4 + r;
                pbest[(size_t)row * NCHUNK + blockIdx.y] = best[j][r];
                pidx [(size_t)row * NCHUNK + blockIdx.y] = bi[j][r];
            }
    }
}

// -------------------------------------------------------------------------
// merge: fold 16 partials/row; ascending chunk order + strict '>' keeps the
// earliest winner -> matches np first-min argmin.
// -------------------------------------------------------------------------
__global__ __launch_bounds__(256) void merge_argmin(const float* __restrict__ pbest,
                                                    const int* __restrict__ pidx,
                                                    int* __restrict__ out)
{
    const long row = (long)blockIdx.x * 256 + threadIdx.x;
    float best = -INFINITY;
    int   bi   = 0;
    #pragma unroll
    for (int i = 0; i < NCHUNK; ++i) {
        float s = pbest[row * NCHUNK + i];
        if (s > best) { best = s; bi = pidx[row * NCHUNK + i]; }
    }
    out[row] = bi;
}

// -------------------------------------------------------------------------
extern "C" void kernel_launch(void* const* d_in, const int* in_sizes, int n_in,
                              void* d_out, int out_size, void* d_ws, size_t ws_size,
                              hipStream_t stream)
{
    const float* x  = (const float*)d_in[0];   // 8*2048*1024
    const float* W  = (const float*)d_in[1];   // 16*1024
    const float* cb = (const float*)d_in[2];   // 8192*16
    int* out = (int*)d_out;                    // 16384 int32

    char* ws = (char*)d_ws;
    unsigned short* zp  = (unsigned short*)ws;               // 1.5 MB
    unsigned short* cbp = (unsigned short*)(ws + 0x180000);  // 768 KB (8192*48*2B)
    float* nhc  = (float*)(ws + 0x240000);                   // 32 KB
    unsigned short* wb = (unsigned short*)(ws + 0x248000);   // 96 KB
    float* pbest = (float*)(ws + 0x260000);                  // 1 MB
    int*   pidx  = (int*)  (ws + 0x360000);                  // 1 MB

    pack_all<<<56, 256, 0, stream>>>(W, cb, wb, cbp, nhc);
    proj_ln <<<ROWS / 16, 256, 0, stream>>>(x, wb, zp);
    dist_argmin<<<dim3(ROWS / 256, NCHUNK), 512, 0, stream>>>(zp, cbp, nhc, pbest, pidx);
    merge_argmin<<<ROWS / 256, 256, 0, stream>>>(pbest, pidx, out);
}